// Round 6
// baseline (245.385 us; speedup 1.0000x reference)
//
#include <hip/hip_runtime.h>
#include <math.h>

// Problem: scores = q[2048x768] @ p[16384x768]^T (fp32 in), per-query
// rank-of-target + log-softmax CE + Gaussian rank weight -> mean (scalar).
// R6: B-stationary fp8 GEMM. 256 blocks x 64 passages; pb tile (48 KB)
// resident in LDS for the whole kernel (staged ONCE: 12.6 MB total vs
// 100 MB re-staged in R5). qb (1.5 MB, L2-resident per XCD) streamed
// through a double-buffered 32-KB A tile: per-phase staging 585 cyc from
// L2 < 1242 cyc MFMA -> compute-bound phases.

#define BQ 2048
#define DD 768
#define NPASS 8
#define PP 16384
#define BM 256             // m-chunk (queries per inner pass)
#define BN 64              // passages per block (stationary)
#define BK 128             // k per A-phase
#define MCH 8              // BQ/BM
#define KT 6               // DD/BK
#define NPH 48             // MCH*KT
#define NBLK 256           // PP/BN
#define NCHUNKS 256        // one partial per block per query

#define ALPHA_C 2.6f
#define INV_2SIG2 (1.0f/6.48f)   // 1/(2*1.8^2)

typedef __attribute__((ext_vector_type(4))) float floatx4;  // MFMA C/D

// ---------------------------------------------------------------------------
// Kernel 1 (fused): cast q,p -> fp8 e4m3  +  s_t exact-fp32 dots  +  out=0.
// ---------------------------------------------------------------------------
#define NQ8   196608     // 2048*768/8
#define NTOT8 1769472    // (2048+16384)*768/8
#define NCB   6912       // NTOT8/256
__global__ __launch_bounds__(256) void prep_kernel(const float* __restrict__ qf,
                                                   const float* __restrict__ pf,
                                                   uint2* __restrict__ qb,
                                                   uint2* __restrict__ pb,
                                                   float* __restrict__ st,
                                                   float* __restrict__ out) {
  const int b = blockIdx.x;
  if (b == 0 && threadIdx.x == 0) *out = 0.f;
  if (b < NCB) {
    const int i = b * 256 + threadIdx.x;        // float8 index
    const float4* src; uint2* dst;
    if (i < NQ8) { src = (const float4*)qf + 2 * (size_t)i; dst = qb + i; }
    else { const size_t j = (size_t)i - NQ8; src = (const float4*)pf + 2 * j; dst = pb + j; }
    const float4 a = src[0], c = src[1];
    unsigned lo = __builtin_amdgcn_cvt_pk_fp8_f32(a.x, a.y, 0, 0);
    lo = __builtin_amdgcn_cvt_pk_fp8_f32(a.z, a.w, lo, 1);
    unsigned hi = __builtin_amdgcn_cvt_pk_fp8_f32(c.x, c.y, 0, 0);
    hi = __builtin_amdgcn_cvt_pk_fp8_f32(c.z, c.w, hi, 1);
    uint2 w; w.x = lo; w.y = hi;
    *dst = w;
  } else {
    const int wv = threadIdx.x >> 6, lane = threadIdx.x & 63;
    const int qi = (b - NCB) * 4 + wv;
    const float4* q4 = (const float4*)(qf + (size_t)qi * DD);
    const float4* p4 = (const float4*)(pf + (size_t)qi * NPASS * DD);
    float acc = 0.f;
#pragma unroll
    for (int u = 0; u < 3; ++u) {
      float4 a = q4[lane + 64 * u];
      float4 c = p4[lane + 64 * u];
      acc = fmaf(a.x, c.x, acc);
      acc = fmaf(a.y, c.y, acc);
      acc = fmaf(a.z, c.z, acc);
      acc = fmaf(a.w, c.w, acc);
    }
#pragma unroll
    for (int off = 32; off >= 1; off >>= 1) acc += __shfl_xor(acc, off);
    if (lane == 0) st[qi] = acc;
  }
}

// ---------------------------------------------------------------------------
// Kernel 2: B-stationary fp8 MFMA GEMM + fused softmax/rank epilogue.
// 16 waves as 4 wm x 4 wn. Wave (wm,wn): rows wm*64..+64, cols wn*16..+16 of
// the current 256x64 m-chunk; 4 MFMAs of 16x16x32 fp8 per 32-k step.
// LDS unit = 16 rows x 64 k-bytes = 1 KB, staged wave-uniform-base+lane*16
// (global_load_lds), layout [kgrp(16B)][row][byte] (R4/R5-validated):
//   frag intra = ((ks&1)*2+(lq>>1))*256 + lm*16 + (lq&1)*8  (ds_read_b64)
// Bs: 48 units (4 colgrps x 12 ku), resident. As: dbuf x 32 units (16 rowgrp
// x 2 kh). C/D: col=lane&15, row=(lane>>4)*4+reg.
// Per m-chunk epilogue: per-wave 16-col stats -> LDS merge over 4 wn ->
// one partial per (query, block): pm/pl/pc[qg*256 + bid].
// ---------------------------------------------------------------------------
__global__ __launch_bounds__(1024) void gemm_kernel(const unsigned char* __restrict__ qb,
                                                    const unsigned char* __restrict__ pb,
                                                    const float* __restrict__ st,
                                                    float* __restrict__ pm,
                                                    float* __restrict__ pl,
                                                    float* __restrict__ pc) {
  __shared__ unsigned char Bs[48 * 1024];      // resident pb tile, 48 KB
  __shared__ unsigned char As[2][32 * 1024];   // dbuf qb m-chunk k-phase, 64 KB
  __shared__ float st_lds[2][BM];              // dbuf st per m-chunk, 2 KB
  __shared__ float stats[BM][12];              // [row][wn*3 + {mx,sum,cnt}], 12 KB

  const int t = threadIdx.x;
  const int lane = t & 63;
  const int wv = t >> 6;            // 0..15
  const int wm = wv >> 2, wn = wv & 3;
  const int bid = blockIdx.x;
  const int n0 = bid * BN;
  const int lm = lane & 15;
  const int lq = lane >> 4;
  const int lds_lane = lane * 16;

  // ---- prestage resident pb tile: 48 units, 3 per wave ----
#pragma unroll
  for (int s = 0; s < 3; ++s) {
    const int u = wv * 3 + s;
    const int cg = u / 12, ku = u % 12;
    const size_t g = (size_t)(n0 + cg * 16 + lm) * DD + ku * 64 + lq * 16;
    __builtin_amdgcn_global_load_lds(
        (const __attribute__((address_space(1))) void*)(pb + g),
        (__attribute__((address_space(3))) void*)(Bs + u * 1024 + lds_lane), 16, 0, 0);
  }
  // ---- prestage A phase 0 (mc=0, kt=0) into buf 0 ----
#pragma unroll
  for (int kh = 0; kh < 2; ++kh) {
    const size_t g = (size_t)(wv * 16 + lm) * DD + kh * 64 + lq * 16;
    __builtin_amdgcn_global_load_lds(
        (const __attribute__((address_space(1))) void*)(qb + g),
        (__attribute__((address_space(3))) void*)(As[0] + (wv * 2 + kh) * 1024 + lds_lane), 16, 0, 0);
  }

  for (int mc = 0; mc < MCH; ++mc) {
    floatx4 acc[4];
#pragma unroll
    for (int i = 0; i < 4; ++i) acc[i] = (floatx4){0.f, 0.f, 0.f, 0.f};

    for (int kt = 0; kt < KT; ++kt) {
      const int ph = mc * KT + kt;
      __syncthreads();               // drains staged loads for this phase
      if (kt == 0 && t < BM) st_lds[mc & 1][t] = st[mc * BM + t];
      if (ph + 1 < NPH) {            // prefetch next phase under compute
        const int nph = ph + 1;
        const int nmc = nph / KT, nkt = nph % KT;
        unsigned char* dst = As[nph & 1];
#pragma unroll
        for (int kh = 0; kh < 2; ++kh) {
          const size_t g = (size_t)(nmc * BM + wv * 16 + lm) * DD + nkt * BK + kh * 64 + lq * 16;
          __builtin_amdgcn_global_load_lds(
              (const __attribute__((address_space(1))) void*)(qb + g),
              (__attribute__((address_space(3))) void*)(dst + (wv * 2 + kh) * 1024 + lds_lane), 16, 0, 0);
        }
      }
      const unsigned char* ab = As[ph & 1];
#pragma unroll
      for (int ks = 0; ks < 4; ++ks) {
        const int intra = ((ks & 1) * 2 + (lq >> 1)) * 256 + lm * 16 + (lq & 1) * 8;
        const int ku = kt * 2 + (ks >> 1);
        long a[4], b;
        b = *(const long*)(Bs + (wn * 12 + ku) * 1024 + intra);
#pragma unroll
        for (int i = 0; i < 4; ++i)
          a[i] = *(const long*)(ab + ((wm * 4 + i) * 2 + (ks >> 1)) * 1024 + intra);
#pragma unroll
        for (int i = 0; i < 4; ++i)
          acc[i] = __builtin_amdgcn_mfma_f32_16x16x32_fp8_fp8(a[i], b, acc[i], 0, 0, 0);
      }
    }

    // ---- epilogue for this m-chunk: per-wave stats over 16 cols ----
#pragma unroll
    for (int i = 0; i < 4; ++i) {
#pragma unroll
      for (int r = 0; r < 4; ++r) {
        const int rl = wm * 64 + i * 16 + lq * 4 + r;   // local query row
        const int qg = mc * BM + rl;
        const float s = acc[i][r];
        const float stv = st_lds[mc & 1][rl];
        const int cg = n0 + wn * 16 + lm;
        const bool pred = (s > stv) && (cg != qg * NPASS);
        const unsigned long long bal = __ballot(pred ? 1 : 0);
        const float c = (float)__popcll((bal >> (lq * 16)) & 0xFFFFull);
        float mx = s;
#pragma unroll
        for (int off = 1; off <= 8; off <<= 1) mx = fmaxf(mx, __shfl_xor(mx, off));
        float sum = __expf(s - mx);
#pragma unroll
        for (int off = 1; off <= 8; off <<= 1) sum += __shfl_xor(sum, off);
        if (lm == 0) {
          stats[rl][wn * 3 + 0] = mx;
          stats[rl][wn * 3 + 1] = sum;
          stats[rl][wn * 3 + 2] = c;
        }
      }
    }
    __syncthreads();
    if (t < BM) {   // merge 4 wn-partials -> one per (query, block)
      const int qg = mc * BM + t;
      float m0 = stats[t][0], m1 = stats[t][3], m2 = stats[t][6], m3 = stats[t][9];
      float mn = fmaxf(fmaxf(m0, m1), fmaxf(m2, m3));
      float l = stats[t][1] * __expf(m0 - mn) + stats[t][4] * __expf(m1 - mn) +
                stats[t][7] * __expf(m2 - mn) + stats[t][10] * __expf(m3 - mn);
      float c = stats[t][2] + stats[t][5] + stats[t][8] + stats[t][11];
      const size_t idx = (size_t)qg * NCHUNKS + bid;
      pm[idx] = mn; pl[idx] = l; pc[idx] = c;
    }
  }
}

// ---------------------------------------------------------------------------
// Kernel 3: merge 256 chunks/query, weighted CE, mean -> atomicAdd. 1 wave/query.
// ---------------------------------------------------------------------------
__global__ __launch_bounds__(256) void finalize_kernel(const float* __restrict__ st,
                                                       const float* __restrict__ pm,
                                                       const float* __restrict__ pl,
                                                       const float* __restrict__ pc,
                                                       float* __restrict__ out) {
  const int wv = threadIdx.x >> 6, lane = threadIdx.x & 63;
  const int qi = blockIdx.x * 4 + wv;
  float4 m4 = ((const float4*)(pm + (size_t)qi * NCHUNKS))[lane];
  float mx = fmaxf(fmaxf(m4.x, m4.y), fmaxf(m4.z, m4.w));
#pragma unroll
  for (int off = 32; off >= 1; off >>= 1) mx = fmaxf(mx, __shfl_xor(mx, off));
  float4 l4 = ((const float4*)(pl + (size_t)qi * NCHUNKS))[lane];
  float4 c4 = ((const float4*)(pc + (size_t)qi * NCHUNKS))[lane];
  float l = l4.x * __expf(m4.x - mx) + l4.y * __expf(m4.y - mx) +
            l4.z * __expf(m4.z - mx) + l4.w * __expf(m4.w - mx);
  float c = c4.x + c4.y + c4.z + c4.w;
#pragma unroll
  for (int off = 32; off >= 1; off >>= 1) {
    l += __shfl_xor(l, off);
    c += __shfl_xor(c, off);
  }
  float loss = 0.f;
  if (lane == 0) {
    const float raw = logf(l) + mx - st[qi];   // -log_softmax[target]
    const float dr = c - 1.0f;                 // rank - OPTIMAL_RANK
    const float w = 1.0f + ALPHA_C * __expf(-(dr * dr) * INV_2SIG2);
    loss = raw * w * (1.0f / (float)BQ);
  }
  __shared__ float red[4];
  if (lane == 0) red[wv] = loss;
  __syncthreads();
  if (threadIdx.x == 0) atomicAdd(out, red[0] + red[1] + red[2] + red[3]);
}

// ---------------------------------------------------------------------------
extern "C" void kernel_launch(void* const* d_in, const int* in_sizes, int n_in,
                              void* d_out, int out_size, void* d_ws, size_t ws_size,
                              hipStream_t stream) {
  const float* q = (const float*)d_in[0];
  const float* p = (const float*)d_in[1];
  char* ws = (char*)d_ws;
  unsigned char* qb = (unsigned char*)ws;                  // 1,572,864 B
  unsigned char* pb = (unsigned char*)(ws + 1572864);      // 12,582,912 B
  float* st = (float*)(ws + 14155776);                     // 8 KB
  float* pm = (float*)(ws + 14163968);                     // 2 MB
  float* pl = (float*)(ws + 16261120);                     // 2 MB
  float* pc = (float*)(ws + 18358272);                     // 2 MB (end ~20.5 MB)
  float* out = (float*)d_out;

  prep_kernel<<<NCB + BQ / 4, 256, 0, stream>>>(q, p, (uint2*)qb, (uint2*)pb, st, out);
  gemm_kernel<<<NBLK, 1024, 0, stream>>>(qb, pb, st, pm, pl, pc);
  finalize_kernel<<<BQ / 4, 256, 0, stream>>>(st, pm, pl, pc, out);
}

// Round 7
// 183.884 us; speedup vs baseline: 1.3345x; 1.3345x over previous
//
#include <hip/hip_runtime.h>
#include <math.h>

// Problem: scores = q[2048x768] @ p[16384x768]^T (fp32 in), per-query
// rank-of-target + log-softmax CE + Gaussian rank weight -> mean (scalar).
// R7 (= R5 structure + co-residency + B-sharing swizzle):
//  - 256x128 tile, 8 waves (4 wm x 2 wn), BK=64 double-buffered (50 KB LDS)
//    -> 2 blocks/CU co-resident; launch_bounds(512,4) caps VGPR at 128
//    (R4 lesson: (1024,8) -> 64 VGPR -> acc spilled to scratch).
//  - grid swizzle nb=bid&127, mb=bid>>7: XCD x sees only 16 B-tiles
//    (1.6 MB, L2-resident) -> staging comes from L2, not L3.
//  - R6 lesson: B-stationary cut global bytes but destroyed MFMA:ds_read
//    ratio (conflicts 5x, VALU>MFMA). Keep 16 MFMA : 8 ds_read_b64.

#define BQ 2048
#define DD 768
#define NPASS 8
#define PP 16384
#define BM 256
#define BN 128
#define BK 64
#define KITERS 12          // 768/64
#define NBLK 128           // PP/BN
#define MBLK 8             // BQ/BM
#define NCHUNKS 256        // NBLK * 2 wn-groups

#define ALPHA_C 2.6f
#define INV_2SIG2 (1.0f/6.48f)   // 1/(2*1.8^2)

typedef __attribute__((ext_vector_type(4))) float floatx4;  // MFMA C/D

// ---------------------------------------------------------------------------
// Kernel 1 (fused): cast q,p -> fp8 e4m3  +  s_t exact-fp32 dots  +  out=0.
// ---------------------------------------------------------------------------
#define NQ8   196608     // 2048*768/8
#define NTOT8 1769472    // (2048+16384)*768/8
#define NCB   6912       // NTOT8/256
__global__ __launch_bounds__(256) void prep_kernel(const float* __restrict__ qf,
                                                   const float* __restrict__ pf,
                                                   uint2* __restrict__ qb,
                                                   uint2* __restrict__ pb,
                                                   float* __restrict__ st,
                                                   float* __restrict__ out) {
  const int b = blockIdx.x;
  if (b == 0 && threadIdx.x == 0) *out = 0.f;
  if (b < NCB) {
    const int i = b * 256 + threadIdx.x;        // float8 index
    const float4* src; uint2* dst;
    if (i < NQ8) { src = (const float4*)qf + 2 * (size_t)i; dst = qb + i; }
    else { const size_t j = (size_t)i - NQ8; src = (const float4*)pf + 2 * j; dst = pb + j; }
    const float4 a = src[0], c = src[1];
    unsigned lo = __builtin_amdgcn_cvt_pk_fp8_f32(a.x, a.y, 0, 0);
    lo = __builtin_amdgcn_cvt_pk_fp8_f32(a.z, a.w, lo, 1);
    unsigned hi = __builtin_amdgcn_cvt_pk_fp8_f32(c.x, c.y, 0, 0);
    hi = __builtin_amdgcn_cvt_pk_fp8_f32(c.z, c.w, hi, 1);
    uint2 w; w.x = lo; w.y = hi;
    *dst = w;
  } else {
    const int wv = threadIdx.x >> 6, lane = threadIdx.x & 63;
    const int qi = (b - NCB) * 4 + wv;
    const float4* q4 = (const float4*)(qf + (size_t)qi * DD);
    const float4* p4 = (const float4*)(pf + (size_t)qi * NPASS * DD);
    float acc = 0.f;
#pragma unroll
    for (int u = 0; u < 3; ++u) {
      float4 a = q4[lane + 64 * u];
      float4 c = p4[lane + 64 * u];
      acc = fmaf(a.x, c.x, acc);
      acc = fmaf(a.y, c.y, acc);
      acc = fmaf(a.z, c.z, acc);
      acc = fmaf(a.w, c.w, acc);
    }
#pragma unroll
    for (int off = 32; off >= 1; off >>= 1) acc += __shfl_xor(acc, off);
    if (lane == 0) st[qi] = acc;
  }
}

// ---------------------------------------------------------------------------
// Kernel 2: fp8 MFMA GEMM 256x128, BK=64 dbuf, 2 blocks/CU co-resident.
// 8 waves as 4 wm x 2 wn; each wave 4x4 MFMAs of 16x16x32 fp8 (64x64 out).
// LDS unit = 16 rows x 64 k-bytes = 1 KB, staged wave-uniform-base+lane*16
// (global_load_lds): lane(lm,lq) -> row lm, kbytes lq*16. Validated intra
// (R4/R5): frag k=ks*32+lq*8+j -> (ks*2+(lq>>1))*256 + lm*16 + (lq&1)*8.
// A = 16 units, B = 8 units per phase; 24 units / 8 waves = 3 each.
// C/D: col=lane&15, row=(lane>>4)*4+reg.
// ---------------------------------------------------------------------------
__global__ __launch_bounds__(512, 4) void gemm_kernel(const unsigned char* __restrict__ qb,
                                                      const unsigned char* __restrict__ pb,
                                                      const float* __restrict__ st,
                                                      float* __restrict__ pm,
                                                      float* __restrict__ pl,
                                                      float* __restrict__ pc) {
  __shared__ unsigned char As[2][16 * 1024];   // [buf][unit][1 KB] = 32 KB
  __shared__ unsigned char Bs[2][8 * 1024];    // 16 KB
  __shared__ float st_lds[BM];

  const int t = threadIdx.x;
  const int lane = t & 63;
  const int wv = t >> 6;            // 0..7
  const int wm = wv >> 1, wn = wv & 1;
  const int bid = blockIdx.x;
  const int nb = bid & 127;         // fast index -> XCD x holds nb===x (mod 8):
  const int mb = bid >> 7;          // 16 B-tiles/XCD (1.6 MB) L2-resident
  const int qbase = mb * BM;
  const int n0 = nb * BN;
  const int lm = lane & 15;
  const int lq = lane >> 4;
  const int lds_lane = lane * 16;

  if (t < BM) st_lds[t] = st[qbase + t];

  floatx4 acc[4][4];
#pragma unroll
  for (int i = 0; i < 4; ++i)
#pragma unroll
    for (int j = 0; j < 4; ++j) acc[i][j] = (floatx4){0.f, 0.f, 0.f, 0.f};

  // stage(kt,buf): 3 units/wave of the 24 (A:16, B:8)
#define STAGE(KT, BUF)                                                           \
  {                                                                              \
    const int koff = (KT) * BK + lq * 16;                                        \
    _Pragma("unroll")                                                            \
    for (int s = 0; s < 3; ++s) {                                                \
      const int u = wv * 3 + s;                                                  \
      if (u < 16) {                                                              \
        __builtin_amdgcn_global_load_lds(                                        \
            (const __attribute__((address_space(1))) void*)(qb + (size_t)(qbase + u * 16 + lm) * DD + koff), \
            (__attribute__((address_space(3))) void*)(&As[BUF][u * 1024] + lds_lane), 16, 0, 0); \
      } else {                                                                   \
        __builtin_amdgcn_global_load_lds(                                        \
            (const __attribute__((address_space(1))) void*)(pb + (size_t)(n0 + (u - 16) * 16 + lm) * DD + koff), \
            (__attribute__((address_space(3))) void*)(&Bs[BUF][(u - 16) * 1024] + lds_lane), 16, 0, 0); \
      }                                                                          \
    }                                                                            \
  }

  STAGE(0, 0)
  for (int kt = 0; kt < KITERS; ++kt) {
    const int cb = kt & 1;
    __syncthreads();                 // drains vmcnt -> buf cb ready
    if (kt < KITERS - 1) STAGE(kt + 1, cb ^ 1)   // flies under compute below
#pragma unroll
    for (int ks = 0; ks < 2; ++ks) {
      const int intra = (ks * 2 + (lq >> 1)) * 256 + lm * 16 + (lq & 1) * 8;
      long a[4], b[4];
#pragma unroll
      for (int i = 0; i < 4; ++i)
        a[i] = *(const long*)(&As[cb][(wm * 4 + i) * 1024] + intra);
#pragma unroll
      for (int j = 0; j < 4; ++j)
        b[j] = *(const long*)(&Bs[cb][(wn * 4 + j) * 1024] + intra);
#pragma unroll
      for (int i = 0; i < 4; ++i)
#pragma unroll
        for (int j = 0; j < 4; ++j)
          acc[i][j] = __builtin_amdgcn_mfma_f32_16x16x32_fp8_fp8(a[i], b[j], acc[i][j], 0, 0, 0);
    }
  }

  // ---- fused epilogue: per-row (query) max / sumexp / count over 64 cols ----
#pragma unroll
  for (int i = 0; i < 4; ++i) {
#pragma unroll
    for (int r = 0; r < 4; ++r) {
      const int rl = wm * 64 + i * 16 + lq * 4 + r;   // local query row
      float mx = fmaxf(fmaxf(acc[i][0][r], acc[i][1][r]),
                       fmaxf(acc[i][2][r], acc[i][3][r]));
#pragma unroll
      for (int off = 1; off <= 8; off <<= 1) mx = fmaxf(mx, __shfl_xor(mx, off));
      const float stv = st_lds[rl];
      const int qg = qbase + rl;
      const int tcol = qg * NPASS;
      float sum = 0.f, c = 0.f;
#pragma unroll
      for (int j = 0; j < 4; ++j) {
        const float s = acc[i][j][r];
        sum += __expf(s - mx);
        const int cg = n0 + wn * 64 + j * 16 + lm;
        if (s > stv && cg != tcol) c += 1.f;
      }
#pragma unroll
      for (int off = 1; off <= 8; off <<= 1) {
        sum += __shfl_xor(sum, off);
        c += __shfl_xor(c, off);
      }
      if (lm == 0) {
        const int chunk = nb * 2 + wn;
        const size_t idx = (size_t)qg * NCHUNKS + chunk;
        pm[idx] = mx; pl[idx] = sum; pc[idx] = c;
      }
    }
  }
}

// ---------------------------------------------------------------------------
// Kernel 3: merge 256 chunks/query, weighted CE, mean -> atomicAdd. 1 wave/query.
// ---------------------------------------------------------------------------
__global__ __launch_bounds__(256) void finalize_kernel(const float* __restrict__ st,
                                                       const float* __restrict__ pm,
                                                       const float* __restrict__ pl,
                                                       const float* __restrict__ pc,
                                                       float* __restrict__ out) {
  const int wv = threadIdx.x >> 6, lane = threadIdx.x & 63;
  const int qi = blockIdx.x * 4 + wv;
  float4 m4 = ((const float4*)(pm + (size_t)qi * NCHUNKS))[lane];
  float mx = fmaxf(fmaxf(m4.x, m4.y), fmaxf(m4.z, m4.w));
#pragma unroll
  for (int off = 32; off >= 1; off >>= 1) mx = fmaxf(mx, __shfl_xor(mx, off));
  float4 l4 = ((const float4*)(pl + (size_t)qi * NCHUNKS))[lane];
  float4 c4 = ((const float4*)(pc + (size_t)qi * NCHUNKS))[lane];
  float l = l4.x * __expf(m4.x - mx) + l4.y * __expf(m4.y - mx) +
            l4.z * __expf(m4.z - mx) + l4.w * __expf(m4.w - mx);
  float c = c4.x + c4.y + c4.z + c4.w;
#pragma unroll
  for (int off = 32; off >= 1; off >>= 1) {
    l += __shfl_xor(l, off);
    c += __shfl_xor(c, off);
  }
  float loss = 0.f;
  if (lane == 0) {
    const float raw = logf(l) + mx - st[qi];   // -log_softmax[target]
    const float dr = c - 1.0f;                 // rank - OPTIMAL_RANK
    const float w = 1.0f + ALPHA_C * __expf(-(dr * dr) * INV_2SIG2);
    loss = raw * w * (1.0f / (float)BQ);
  }
  __shared__ float red[4];
  if (lane == 0) red[wv] = loss;
  __syncthreads();
  if (threadIdx.x == 0) atomicAdd(out, red[0] + red[1] + red[2] + red[3]);
}

// ---------------------------------------------------------------------------
extern "C" void kernel_launch(void* const* d_in, const int* in_sizes, int n_in,
                              void* d_out, int out_size, void* d_ws, size_t ws_size,
                              hipStream_t stream) {
  const float* q = (const float*)d_in[0];
  const float* p = (const float*)d_in[1];
  char* ws = (char*)d_ws;
  unsigned char* qb = (unsigned char*)ws;                  // 1,572,864 B
  unsigned char* pb = (unsigned char*)(ws + 1572864);      // 12,582,912 B
  float* st = (float*)(ws + 14155776);                     // 8 KB
  float* pm = (float*)(ws + 14163968);                     // 2 MB
  float* pl = (float*)(ws + 16261120);                     // 2 MB
  float* pc = (float*)(ws + 18358272);                     // 2 MB (end ~20.5 MB)
  float* out = (float*)d_out;

  prep_kernel<<<NCB + BQ / 4, 256, 0, stream>>>(q, p, (uint2*)qb, (uint2*)pb, st, out);
  gemm_kernel<<<NBLK * MBLK, 512, 0, stream>>>(qb, pb, st, pm, pl, pc);
  finalize_kernel<<<BQ / 4, 256, 0, stream>>>(st, pm, pl, pc, out);
}